// Round 4
// baseline (1894.389 us; speedup 1.0000x reference)
//
#include <hip/hip_runtime.h>
#include <math.h>

#define HH 192
#define WW 192
#define HWP (192*192)
#define BB 4
#define CF 64
#define NC 7
#define OO 64
#define PIX_BLOCKS (HWP/256)   // 144

typedef float f32x16 __attribute__((ext_vector_type(16)));

// ---------------- depthwise conv (SAME, groups=C) ----------------
template<int k>
__global__ __launch_bounds__(256)
void dw_kernel(const float* __restrict__ fea, const float* __restrict__ w,
               const float* __restrict__ bias, float* __restrict__ out) {
    int idx = blockIdx.x * 256 + threadIdx.x;   // over B*CF*HW
    if (idx >= BB * CF * HWP) return;
    int wpos = idx % WW;
    int hpos = (idx / WW) % HH;
    int plane = idx / HWP;        // b*CF + c
    int c = plane % CF;
    const float* f = fea + (size_t)plane * HWP;
    const int pad = k / 2;
    float acc = 0.f;
#pragma unroll
    for (int dy = 0; dy < k; ++dy) {
        int y = hpos + dy - pad;
        if (y < 0 || y >= HH) continue;
#pragma unroll
        for (int dx = 0; dx < k; ++dx) {
            int x = wpos + dx - pad;
            if (x < 0 || x >= WW) continue;
            acc += f[y * WW + x] * w[c * k * k + dy * k + dx];
        }
    }
    out[idx] = acc + bias[c];
}

// ---------------- generic small transpose (rows,cols) -> (cols,rows) ------
__global__ void transpose_kernel(const float* __restrict__ in, float* __restrict__ out,
                                 int rows, int cols) {
    int idx = blockIdx.x * 256 + threadIdx.x;
    if (idx >= rows * cols) return;
    int r = idx / cols, c = idx % cols;
    out[c * rows + r] = in[idx];
}

// ---------------- fused pw-conv (offset/mask) + deformable conv + relu ----
// Round-2 lesson: VGPR=108 < 64(dw)+64(acc) proves the compiler was
// re-loading dw from global every inner iteration (legal: const __restrict__
// loads are sinkable/rematerializable). The empty asm "+v" barrier below
// makes the loaded values opaque so they MUST stay register-resident.
template<int k>
__global__ __launch_bounds__(256, 2)
void branch_kernel(const float* __restrict__ dwout,
                   const float* __restrict__ pw_w, const float* __restrict__ pw_b,
                   const float* __restrict__ inputs,
                   const float* __restrict__ dcn_wt,   // (7K, 64)
                   const float* __restrict__ dcn_b,
                   float* __restrict__ outbuf, int t) {
    constexpr int K = k * k;
    constexpr int pad = k / 2;
    int blk = blockIdx.x;                 // 0..575
    int b = blk / PIX_BLOCKS;
    int p = (blk % PIX_BLOCKS) * 256 + threadIdx.x;
    int h = p / WW, wq = p % WW;

    // per-pixel dw vector, register-resident
    f32x16 dwv0, dwv1, dwv2, dwv3;
    {
        const float* dwp = dwout + (size_t)(b * CF) * HWP + p;
#pragma unroll
        for (int j = 0; j < 16; ++j) dwv0[j] = dwp[(size_t)(j) * HWP];
#pragma unroll
        for (int j = 0; j < 16; ++j) dwv1[j] = dwp[(size_t)(16 + j) * HWP];
#pragma unroll
        for (int j = 0; j < 16; ++j) dwv2[j] = dwp[(size_t)(32 + j) * HWP];
#pragma unroll
        for (int j = 0; j < 16; ++j) dwv3[j] = dwp[(size_t)(48 + j) * HWP];
    }
    // Pin: forbid re-materialization / load-sinking of the dw values.
    asm volatile("" : "+v"(dwv0));
    asm volatile("" : "+v"(dwv1));
    asm volatile("" : "+v"(dwv2));
    asm volatile("" : "+v"(dwv3));

    f32x16 acc0, acc1, acc2, acc3;
#pragma unroll
    for (int j = 0; j < 16; ++j) { acc0[j] = 0.f; acc1[j] = 0.f; acc2[j] = 0.f; acc3[j] = 0.f; }

    const float* inb = inputs + (size_t)b * NC * HWP;

    for (int c = 0; c < NC; ++c) {
        const float* inc_ = inb + (size_t)c * HWP;
        for (int kk = 0; kk < K; ++kk) {
            int r = c * K + kk;                       // uniform
            const float* wy = pw_w + (size_t)(2 * r) * CF;
            const float* wx = wy + CF;
            const float* wm = pw_w + (size_t)(2 * NC * K + r) * CF;
            float oy = pw_b[2 * r];
            float ox = pw_b[2 * r + 1];
            float om = pw_b[2 * NC * K + r];
            // 3 dot products over 64; weights wave-uniform -> SGPR operand
#pragma unroll
            for (int j = 0; j < 16; ++j) {
                oy += wy[j] * dwv0[j];  ox += wx[j] * dwv0[j];  om += wm[j] * dwv0[j];
            }
#pragma unroll
            for (int j = 0; j < 16; ++j) {
                oy += wy[16 + j] * dwv1[j];  ox += wx[16 + j] * dwv1[j];  om += wm[16 + j] * dwv1[j];
            }
#pragma unroll
            for (int j = 0; j < 16; ++j) {
                oy += wy[32 + j] * dwv2[j];  ox += wx[32 + j] * dwv2[j];  om += wm[32 + j] * dwv2[j];
            }
#pragma unroll
            for (int j = 0; j < 16; ++j) {
                oy += wy[48 + j] * dwv3[j];  ox += wx[48 + j] * dwv3[j];  om += wm[48 + j] * dwv3[j];
            }
            float m = 1.f / (1.f + expf(-om));
            float py = oy + (float)(kk / k + h - pad);
            float px = ox + (float)(kk % k + wq - pad);
            float y0 = floorf(py), x0 = floorf(px);
            float wyf = py - y0, wxf = px - x0;
            int iy0 = (int)y0, ix0 = (int)x0;
            bool y0v = (iy0 >= 0) && (iy0 < HH);
            bool y1v = (iy0 + 1 >= 0) && (iy0 + 1 < HH);
            bool x0v = (ix0 >= 0) && (ix0 < WW);
            bool x1v = (ix0 + 1 >= 0) && (ix0 + 1 < WW);
            int yc0 = min(max(iy0, 0), HH - 1), yc1 = min(max(iy0 + 1, 0), HH - 1);
            int xc0 = min(max(ix0, 0), WW - 1), xc1 = min(max(ix0 + 1, 0), WW - 1);
            float v00 = 0.f, v01 = 0.f, v10 = 0.f, v11 = 0.f;
            if (y0v) {
                if (x0v) v00 = inc_[yc0 * WW + xc0];
                if (x1v) v01 = inc_[yc0 * WW + xc1];
            }
            if (y1v) {
                if (x0v) v10 = inc_[yc1 * WW + xc0];
                if (x1v) v11 = inc_[yc1 * WW + xc1];
            }
            float s = (v00 * (1.f - wyf) * (1.f - wxf) + v01 * (1.f - wyf) * wxf +
                       v10 * wyf * (1.f - wxf) + v11 * wyf * wxf) * m;
            const float* dt = dcn_wt + (size_t)r * OO;   // uniform row
#pragma unroll
            for (int j = 0; j < 16; ++j) acc0[j] += s * dt[j];
#pragma unroll
            for (int j = 0; j < 16; ++j) acc1[j] += s * dt[16 + j];
#pragma unroll
            for (int j = 0; j < 16; ++j) acc2[j] += s * dt[32 + j];
#pragma unroll
            for (int j = 0; j < 16; ++j) acc3[j] += s * dt[48 + j];
        }
    }
    float* op = outbuf + (size_t)((b * 3 + t) * OO) * HWP + p;
#pragma unroll
    for (int j = 0; j < 16; ++j) {
        float v = acc0[j] + dcn_b[j];
        op[(size_t)j * HWP] = v > 0.f ? v : 0.f;
    }
#pragma unroll
    for (int j = 0; j < 16; ++j) {
        float v = acc1[j] + dcn_b[16 + j];
        op[(size_t)(16 + j) * HWP] = v > 0.f ? v : 0.f;
    }
#pragma unroll
    for (int j = 0; j < 16; ++j) {
        float v = acc2[j] + dcn_b[32 + j];
        op[(size_t)(32 + j) * HWP] = v > 0.f ? v : 0.f;
    }
#pragma unroll
    for (int j = 0; j < 16; ++j) {
        float v = acc3[j] + dcn_b[48 + j];
        op[(size_t)(48 + j) * HWP] = v > 0.f ? v : 0.f;
    }
}

// ---------------- attention: per-block partial sums of relu(attn pw) ------
__global__ __launch_bounds__(256, 2)
void attn_sum_kernel(const float* __restrict__ outbuf, const float* __restrict__ attn_wt,
                     const float* __restrict__ attn_b, float* __restrict__ partial) {
    int blk = blockIdx.x;
    int b = blk / PIX_BLOCKS;
    int pb = blk % PIX_BLOCKS;
    int p = pb * 256 + threadIdx.x;
    const float* ob = outbuf + (size_t)(b * 192) * HWP + p;
    f32x16 a0, a1, a2, a3;
#pragma unroll
    for (int j = 0; j < 16; ++j) {
        a0[j] = attn_b[j]; a1[j] = attn_b[16 + j]; a2[j] = attn_b[32 + j]; a3[j] = attn_b[48 + j];
    }
    for (int c = 0; c < 192; ++c) {
        float v = ob[(size_t)c * HWP];
        const float* wt = attn_wt + c * OO;
#pragma unroll
        for (int j = 0; j < 16; ++j) a0[j] += v * wt[j];
#pragma unroll
        for (int j = 0; j < 16; ++j) a1[j] += v * wt[16 + j];
#pragma unroll
        for (int j = 0; j < 16; ++j) a2[j] += v * wt[32 + j];
#pragma unroll
        for (int j = 0; j < 16; ++j) a3[j] += v * wt[48 + j];
    }
    __shared__ float red[4][OO];
    int lane = threadIdx.x & 63, wv = threadIdx.x >> 6;
#pragma unroll
    for (int o = 0; o < OO; ++o) {
        float v = (o < 16) ? a0[o & 15] : (o < 32) ? a1[o & 15] : (o < 48) ? a2[o & 15] : a3[o & 15];
        v = v > 0.f ? v : 0.f;
        v += __shfl_down(v, 32);
        v += __shfl_down(v, 16);
        v += __shfl_down(v, 8);
        v += __shfl_down(v, 4);
        v += __shfl_down(v, 2);
        v += __shfl_down(v, 1);
        if (lane == 0) red[wv][o] = v;
    }
    __syncthreads();
    if (threadIdx.x < OO) {
        int o = threadIdx.x;
        partial[(size_t)(b * PIX_BLOCKS + pb) * OO + o] =
            red[0][o] + red[1][o] + red[2][o] + red[3][o];
    }
}

// ---------------- attention finish: mean -> fc(relu) -> per-branch scales -
__global__ void attn_finish_kernel(const float* __restrict__ partial,
                                   const float* __restrict__ fc_w, const float* __restrict__ fc_b,
                                   const float* __restrict__ fcs_w0, const float* __restrict__ fcs_b0,
                                   const float* __restrict__ fcs_w1, const float* __restrict__ fcs_b1,
                                   const float* __restrict__ fcs_w2, const float* __restrict__ fcs_b2,
                                   float* __restrict__ atts) {
    int b = blockIdx.x;
    __shared__ float attm[OO];
    __shared__ float fcv[32];
    int tid = threadIdx.x;   // 64 threads
    if (tid < OO) {
        float s = 0.f;
        for (int blk = 0; blk < PIX_BLOCKS; ++blk)
            s += partial[(size_t)(b * PIX_BLOCKS + blk) * OO + tid];
        attm[tid] = s / (float)HWP;
    }
    __syncthreads();
    if (tid < 32) {
        float s = fc_b[tid];
        for (int o = 0; o < OO; ++o) s += fc_w[tid * OO + o] * attm[o];
        fcv[tid] = s > 0.f ? s : 0.f;
    }
    __syncthreads();
    if (tid < OO) {
        {
            float s = fcs_b0[tid];
            for (int j = 0; j < 32; ++j) s += fcs_w0[tid * 32 + j] * fcv[j];
            atts[b * 192 + 0 * OO + tid] = s;
        }
        {
            float s = fcs_b1[tid];
            for (int j = 0; j < 32; ++j) s += fcs_w1[tid * 32 + j] * fcv[j];
            atts[b * 192 + 1 * OO + tid] = s;
        }
        {
            float s = fcs_b2[tid];
            for (int j = 0; j < 32; ++j) s += fcs_w2[tid * 32 + j] * fcv[j];
            atts[b * 192 + 2 * OO + tid] = s;
        }
    }
}

// ---------------- final: scale + 1x1 conv + relu ----------------
__global__ __launch_bounds__(256, 2)
void final_kernel(const float* __restrict__ outbuf, const float* __restrict__ atts,
                  const float* __restrict__ conv_wt, const float* __restrict__ conv_b,
                  float* __restrict__ out) {
    int blk = blockIdx.x;
    int b = blk / PIX_BLOCKS;
    int p = (blk % PIX_BLOCKS) * 256 + threadIdx.x;
    const float* ob = outbuf + (size_t)(b * 192) * HWP + p;
    const float* at = atts + b * 192;
    f32x16 a0, a1, a2, a3;
#pragma unroll
    for (int j = 0; j < 16; ++j) {
        a0[j] = conv_b[j]; a1[j] = conv_b[16 + j]; a2[j] = conv_b[32 + j]; a3[j] = conv_b[48 + j];
    }
    for (int c = 0; c < 192; ++c) {
        float v = ob[(size_t)c * HWP] * at[c];
        const float* wt = conv_wt + c * OO;
#pragma unroll
        for (int j = 0; j < 16; ++j) a0[j] += v * wt[j];
#pragma unroll
        for (int j = 0; j < 16; ++j) a1[j] += v * wt[16 + j];
#pragma unroll
        for (int j = 0; j < 16; ++j) a2[j] += v * wt[32 + j];
#pragma unroll
        for (int j = 0; j < 16; ++j) a3[j] += v * wt[48 + j];
    }
    float* op = out + (size_t)(b * OO) * HWP + p;
#pragma unroll
    for (int j = 0; j < 16; ++j) op[(size_t)j * HWP] = a0[j] > 0.f ? a0[j] : 0.f;
#pragma unroll
    for (int j = 0; j < 16; ++j) op[(size_t)(16 + j) * HWP] = a1[j] > 0.f ? a1[j] : 0.f;
#pragma unroll
    for (int j = 0; j < 16; ++j) op[(size_t)(32 + j) * HWP] = a2[j] > 0.f ? a2[j] : 0.f;
#pragma unroll
    for (int j = 0; j < 16; ++j) op[(size_t)(48 + j) * HWP] = a3[j] > 0.f ? a3[j] : 0.f;
}

extern "C" void kernel_launch(void* const* d_in, const int* in_sizes, int n_in,
                              void* d_out, int out_size, void* d_ws, size_t ws_size,
                              hipStream_t stream) {
    const float* fea    = (const float*)d_in[0];
    const float* inputs = (const float*)d_in[1];
    const float* dw_w[3]  = {(const float*)d_in[2],  (const float*)d_in[8],  (const float*)d_in[14]};
    const float* dw_b[3]  = {(const float*)d_in[3],  (const float*)d_in[9],  (const float*)d_in[15]};
    const float* pw_w[3]  = {(const float*)d_in[4],  (const float*)d_in[10], (const float*)d_in[16]};
    const float* pw_b[3]  = {(const float*)d_in[5],  (const float*)d_in[11], (const float*)d_in[17]};
    const float* dcn_w[3] = {(const float*)d_in[6],  (const float*)d_in[12], (const float*)d_in[18]};
    const float* dcn_b[3] = {(const float*)d_in[7],  (const float*)d_in[13], (const float*)d_in[19]};
    const float* attn_w = (const float*)d_in[20];
    const float* attn_b = (const float*)d_in[21];
    const float* fc_w   = (const float*)d_in[22];
    const float* fc_b   = (const float*)d_in[23];
    const float* fcs_w[3] = {(const float*)d_in[24], (const float*)d_in[26], (const float*)d_in[28]};
    const float* fcs_b[3] = {(const float*)d_in[25], (const float*)d_in[27], (const float*)d_in[29]};
    const float* conv_w = (const float*)d_in[30];
    const float* conv_b = (const float*)d_in[31];
    float* out = (float*)d_out;

    // workspace carve (floats)
    float* W = (float*)d_ws;
    float* outbuf  = W;                         // 4*192*36864 = 28,311,552
    float* dwout   = outbuf + 28311552;         // 4*64*36864  = 9,437,184
    float* partial = dwout + 9437184;           // 4*144*64    = 36,864
    float* atts    = partial + 36864;           // 768
    float* dcn_wt  = atts + 768;                // up to 7*25*64 = 11,200
    float* attn_wt = dcn_wt + 11200;            // 192*64 = 12,288
    float* conv_wt = attn_wt + 12288;           // 192*64 = 12,288

    // transpose 192x64 weight matrices once per call
    transpose_kernel<<<(192 * 64 + 255) / 256, 256, 0, stream>>>(attn_w, attn_wt, 64, 192);
    transpose_kernel<<<(192 * 64 + 255) / 256, 256, 0, stream>>>(conv_w, conv_wt, 64, 192);

    const int dw_grid = (BB * CF * HWP) / 256;   // 36864
    const int pix_grid = BB * PIX_BLOCKS;        // 576

    // branch 0 (k=1)
    dw_kernel<1><<<dw_grid, 256, 0, stream>>>(fea, dw_w[0], dw_b[0], dwout);
    transpose_kernel<<<(7 * 1 * 64 + 255) / 256, 256, 0, stream>>>(dcn_w[0], dcn_wt, 64, 7 * 1);
    branch_kernel<1><<<pix_grid, 256, 0, stream>>>(dwout, pw_w[0], pw_b[0], inputs,
                                                   dcn_wt, dcn_b[0], outbuf, 0);
    // branch 1 (k=3)
    dw_kernel<3><<<dw_grid, 256, 0, stream>>>(fea, dw_w[1], dw_b[1], dwout);
    transpose_kernel<<<(7 * 9 * 64 + 255) / 256, 256, 0, stream>>>(dcn_w[1], dcn_wt, 64, 7 * 9);
    branch_kernel<3><<<pix_grid, 256, 0, stream>>>(dwout, pw_w[1], pw_b[1], inputs,
                                                   dcn_wt, dcn_b[1], outbuf, 1);
    // branch 2 (k=5)
    dw_kernel<5><<<dw_grid, 256, 0, stream>>>(fea, dw_w[2], dw_b[2], dwout);
    transpose_kernel<<<(7 * 25 * 64 + 255) / 256, 256, 0, stream>>>(dcn_w[2], dcn_wt, 64, 7 * 25);
    branch_kernel<5><<<pix_grid, 256, 0, stream>>>(dwout, pw_w[2], pw_b[2], inputs,
                                                   dcn_wt, dcn_b[2], outbuf, 2);

    // attention
    attn_sum_kernel<<<pix_grid, 256, 0, stream>>>(outbuf, attn_wt, attn_b, partial);
    attn_finish_kernel<<<BB, 64, 0, stream>>>(partial, fc_w, fc_b,
                                              fcs_w[0], fcs_b[0], fcs_w[1], fcs_b[1],
                                              fcs_w[2], fcs_b[2], atts);
    // final conv
    final_kernel<<<pix_grid, 256, 0, stream>>>(outbuf, atts, conv_wt, conv_b, out);
}

// Round 5
// 1487.802 us; speedup vs baseline: 1.2733x; 1.2733x over previous
//
#include <hip/hip_runtime.h>
#include <math.h>

#define HH 192
#define WW 192
#define HWP (192*192)
#define BB 4
#define CF 64
#define NC 7
#define OO 64
#define PIX_BLOCKS (HWP/256)   // 144

typedef float f32x16 __attribute__((ext_vector_type(16)));

// ---------------- standalone depthwise conv (fallback path) ----------------
template<int k>
__global__ __launch_bounds__(256)
void dw_kernel(const float* __restrict__ fea, const float* __restrict__ w,
               const float* __restrict__ bias, float* __restrict__ out) {
    int idx = blockIdx.x * 256 + threadIdx.x;   // over B*CF*HW
    if (idx >= BB * CF * HWP) return;
    int wpos = idx % WW;
    int hpos = (idx / WW) % HH;
    int plane = idx / HWP;        // b*CF + c
    int c = plane % CF;
    const float* f = fea + (size_t)plane * HWP;
    const int pad = k / 2;
    float acc = 0.f;
#pragma unroll
    for (int dy = 0; dy < k; ++dy) {
        int y = hpos + dy - pad;
        if (y < 0 || y >= HH) continue;
#pragma unroll
        for (int dx = 0; dx < k; ++dx) {
            int x = wpos + dx - pad;
            if (x < 0 || x >= WW) continue;
            acc += f[y * WW + x] * w[c * k * k + dy * k + dx];
        }
    }
    out[idx] = acc + bias[c];
}

// ---------------- fused dw conv for k=3 and k=5 (single fea pass) ----------
__global__ __launch_bounds__(256)
void dw35_kernel(const float* __restrict__ fea,
                 const float* __restrict__ w3, const float* __restrict__ b3,
                 const float* __restrict__ w5, const float* __restrict__ b5,
                 float* __restrict__ out3, float* __restrict__ out5) {
    int idx = blockIdx.x * 256 + threadIdx.x;
    if (idx >= BB * CF * HWP) return;
    int wpos = idx % WW;
    int hpos = (idx / WW) % HH;
    int plane = idx / HWP;
    int c = plane % CF;
    const float* f = fea + (size_t)plane * HWP;
    float nv[5][5];
#pragma unroll
    for (int dy = 0; dy < 5; ++dy) {
        int y = hpos + dy - 2;
        bool yv = (y >= 0) && (y < HH);
        int yc = min(max(y, 0), HH - 1);
#pragma unroll
        for (int dx = 0; dx < 5; ++dx) {
            int x = wpos + dx - 2;
            bool v = yv && (x >= 0) && (x < WW);
            int xc = min(max(x, 0), WW - 1);
            float val = f[yc * WW + xc];
            nv[dy][dx] = v ? val : 0.f;
        }
    }
    float a3 = 0.f, a5 = 0.f;
#pragma unroll
    for (int dy = 0; dy < 5; ++dy)
#pragma unroll
        for (int dx = 0; dx < 5; ++dx)
            a5 += nv[dy][dx] * w5[c * 25 + dy * 5 + dx];
#pragma unroll
    for (int dy = 0; dy < 3; ++dy)
#pragma unroll
        for (int dx = 0; dx < 3; ++dx)
            a3 += nv[dy + 1][dx + 1] * w3[c * 9 + dy * 3 + dx];
    out3[idx] = a3 + b3[c];
    out5[idx] = a5 + b5[c];
}

// ---------------- generic small transpose (rows,cols) -> (cols,rows) ------
__global__ void transpose_kernel(const float* __restrict__ in, float* __restrict__ out,
                                 int rows, int cols) {
    int idx = blockIdx.x * 256 + threadIdx.x;
    if (idx >= rows * cols) return;
    int r = idx / cols, c = idx % cols;
    out[c * rows + r] = in[idx];
}

// ---------------- core: pw offsets -> deformable sampling -> acc ----------
template<int k>
__device__ __forceinline__ void branch_compute(
    const f32x16& dwv0, const f32x16& dwv1, const f32x16& dwv2, const f32x16& dwv3,
    const float* __restrict__ pw_w, const float* __restrict__ pw_b,
    const float* __restrict__ inb,        // inputs + b*NC*HWP
    const float* __restrict__ dcn_wt,     // (7K,64)
    int h, int wq, int r0, int r1,
    f32x16& acc0, f32x16& acc1, f32x16& acc2, f32x16& acc3) {
    constexpr int K = k * k;
    constexpr int pad = k / 2;
    int c = r0 / K;
    int kk = r0 % K;
    int ky = kk / k, kx = kk % k;
    for (int r = r0; r < r1; ++r) {
        const float* inc_ = inb + (size_t)c * HWP;
        const float* wy = pw_w + (size_t)(2 * r) * CF;
        const float* wx = wy + CF;
        const float* wm = pw_w + (size_t)(2 * NC * K + r) * CF;
        float oy = pw_b[2 * r], ox = pw_b[2 * r + 1], om = pw_b[2 * NC * K + r];
#pragma unroll
        for (int j = 0; j < 16; ++j) {
            oy += wy[j] * dwv0[j];  ox += wx[j] * dwv0[j];  om += wm[j] * dwv0[j];
        }
#pragma unroll
        for (int j = 0; j < 16; ++j) {
            oy += wy[16 + j] * dwv1[j];  ox += wx[16 + j] * dwv1[j];  om += wm[16 + j] * dwv1[j];
        }
#pragma unroll
        for (int j = 0; j < 16; ++j) {
            oy += wy[32 + j] * dwv2[j];  ox += wx[32 + j] * dwv2[j];  om += wm[32 + j] * dwv2[j];
        }
#pragma unroll
        for (int j = 0; j < 16; ++j) {
            oy += wy[48 + j] * dwv3[j];  ox += wx[48 + j] * dwv3[j];  om += wm[48 + j] * dwv3[j];
        }
        float m = 1.f / (1.f + expf(-om));
        float py = oy + (float)(ky + h - pad);
        float px = ox + (float)(kx + wq - pad);
        float y0 = floorf(py), x0 = floorf(px);
        float wyf = py - y0, wxf = px - x0;
        int iy0 = (int)y0, ix0 = (int)x0;
        bool y0v = (iy0 >= 0) && (iy0 < HH);
        bool y1v = (iy0 + 1 >= 0) && (iy0 + 1 < HH);
        bool x0v = (ix0 >= 0) && (ix0 < WW);
        bool x1v = (ix0 + 1 >= 0) && (ix0 + 1 < WW);
        int yc0 = min(max(iy0, 0), HH - 1), yc1 = min(max(iy0 + 1, 0), HH - 1);
        int xc0 = min(max(ix0, 0), WW - 1), xc1 = min(max(ix0 + 1, 0), WW - 1);
        float v00 = 0.f, v01 = 0.f, v10 = 0.f, v11 = 0.f;
        if (y0v) {
            if (x0v) v00 = inc_[yc0 * WW + xc0];
            if (x1v) v01 = inc_[yc0 * WW + xc1];
        }
        if (y1v) {
            if (x0v) v10 = inc_[yc1 * WW + xc0];
            if (x1v) v11 = inc_[yc1 * WW + xc1];
        }
        float s = (v00 * (1.f - wyf) * (1.f - wxf) + v01 * (1.f - wyf) * wxf +
                   v10 * wyf * (1.f - wxf) + v11 * wyf * wxf) * m;
        const float* dt = dcn_wt + (size_t)r * OO;
#pragma unroll
        for (int j = 0; j < 16; ++j) acc0[j] += s * dt[j];
#pragma unroll
        for (int j = 0; j < 16; ++j) acc1[j] += s * dt[16 + j];
#pragma unroll
        for (int j = 0; j < 16; ++j) acc2[j] += s * dt[32 + j];
#pragma unroll
        for (int j = 0; j < 16; ++j) acc3[j] += s * dt[48 + j];
        if (++kx == k) { kx = 0; if (++ky == k) { ky = 0; ++c; } }
        ++kk;
        if (kk == K) { kk = 0; }
    }
}

__device__ __forceinline__ void store_bias_relu(float* op, const f32x16& a0, const f32x16& a1,
                                                const f32x16& a2, const f32x16& a3,
                                                const float* __restrict__ bias) {
#pragma unroll
    for (int j = 0; j < 16; ++j) { float v = a0[j] + bias[j];      op[(size_t)j * HWP] = v > 0.f ? v : 0.f; }
#pragma unroll
    for (int j = 0; j < 16; ++j) { float v = a1[j] + bias[16 + j]; op[(size_t)(16 + j) * HWP] = v > 0.f ? v : 0.f; }
#pragma unroll
    for (int j = 0; j < 16; ++j) { float v = a2[j] + bias[32 + j]; op[(size_t)(32 + j) * HWP] = v > 0.f ? v : 0.f; }
#pragma unroll
    for (int j = 0; j < 16; ++j) { float v = a3[j] + bias[48 + j]; op[(size_t)(48 + j) * HWP] = v > 0.f ? v : 0.f; }
}

__device__ __forceinline__ void store_raw(float* op, const f32x16& a0, const f32x16& a1,
                                          const f32x16& a2, const f32x16& a3) {
#pragma unroll
    for (int j = 0; j < 16; ++j) op[(size_t)j * HWP] = a0[j];
#pragma unroll
    for (int j = 0; j < 16; ++j) op[(size_t)(16 + j) * HWP] = a1[j];
#pragma unroll
    for (int j = 0; j < 16; ++j) op[(size_t)(32 + j) * HWP] = a2[j];
#pragma unroll
    for (int j = 0; j < 16; ++j) op[(size_t)(48 + j) * HWP] = a3[j];
}

// ---------------- mega branch kernel: all 3 branches, k5 tap-split --------
// kinds: 0 = k5 taps [0,88) -> outbuf t2 raw; 1 = k5 taps [88,175) -> part1 raw
//        2 = k3 full -> outbuf t1 (+bias,relu); 3 = k1 full (inline dw) -> t0
__global__ __launch_bounds__(256)
void mega_branch_kernel(const float* __restrict__ fea,
                        const float* __restrict__ dw_w0, const float* __restrict__ dw_b0,
                        const float* __restrict__ dw3out, const float* __restrict__ dw5out,
                        const float* __restrict__ pw_w0, const float* __restrict__ pw_b0,
                        const float* __restrict__ pw_w1, const float* __restrict__ pw_b1,
                        const float* __restrict__ pw_w2, const float* __restrict__ pw_b2,
                        const float* __restrict__ inputs,
                        const float* __restrict__ dcn_wt0, const float* __restrict__ dcn_b0,
                        const float* __restrict__ dcn_wt1, const float* __restrict__ dcn_b1,
                        const float* __restrict__ dcn_wt2,
                        float* __restrict__ outbuf, float* __restrict__ part1,
                        int kind_force) {
    int gid = blockIdx.x;
    int kind, idx;
    if (kind_force >= 0) { kind = kind_force; idx = gid; }
    else { kind = gid & 3; idx = gid >> 2; }
    int b = idx / PIX_BLOCKS;
    int p = (idx % PIX_BLOCKS) * 256 + threadIdx.x;
    int h = p / WW, wq = p % WW;
    const float* inb = inputs + (size_t)b * NC * HWP;

    f32x16 dwv0, dwv1, dwv2, dwv3;
    if (kind == 3) {
        // k=1 depthwise is per-pixel: fuse it here
        const float* fp = fea + (size_t)(b * CF) * HWP + p;
#pragma unroll
        for (int j = 0; j < 16; ++j) dwv0[j] = fp[(size_t)j * HWP] * dw_w0[j] + dw_b0[j];
#pragma unroll
        for (int j = 0; j < 16; ++j) dwv1[j] = fp[(size_t)(16 + j) * HWP] * dw_w0[16 + j] + dw_b0[16 + j];
#pragma unroll
        for (int j = 0; j < 16; ++j) dwv2[j] = fp[(size_t)(32 + j) * HWP] * dw_w0[32 + j] + dw_b0[32 + j];
#pragma unroll
        for (int j = 0; j < 16; ++j) dwv3[j] = fp[(size_t)(48 + j) * HWP] * dw_w0[48 + j] + dw_b0[48 + j];
    } else {
        const float* dwp = ((kind == 2) ? dw3out : dw5out) + (size_t)(b * CF) * HWP + p;
#pragma unroll
        for (int j = 0; j < 16; ++j) dwv0[j] = dwp[(size_t)j * HWP];
#pragma unroll
        for (int j = 0; j < 16; ++j) dwv1[j] = dwp[(size_t)(16 + j) * HWP];
#pragma unroll
        for (int j = 0; j < 16; ++j) dwv2[j] = dwp[(size_t)(32 + j) * HWP];
#pragma unroll
        for (int j = 0; j < 16; ++j) dwv3[j] = dwp[(size_t)(48 + j) * HWP];
    }

    f32x16 acc0, acc1, acc2, acc3;
#pragma unroll
    for (int j = 0; j < 16; ++j) { acc0[j] = 0.f; acc1[j] = 0.f; acc2[j] = 0.f; acc3[j] = 0.f; }

    if (kind == 3) {
        branch_compute<1>(dwv0, dwv1, dwv2, dwv3, pw_w0, pw_b0, inb, dcn_wt0, h, wq, 0, 7,
                          acc0, acc1, acc2, acc3);
        store_bias_relu(outbuf + (size_t)((b * 3 + 0) * OO) * HWP + p, acc0, acc1, acc2, acc3, dcn_b0);
    } else if (kind == 2) {
        branch_compute<3>(dwv0, dwv1, dwv2, dwv3, pw_w1, pw_b1, inb, dcn_wt1, h, wq, 0, 63,
                          acc0, acc1, acc2, acc3);
        store_bias_relu(outbuf + (size_t)((b * 3 + 1) * OO) * HWP + p, acc0, acc1, acc2, acc3, dcn_b1);
    } else if (kind == 0) {
        branch_compute<5>(dwv0, dwv1, dwv2, dwv3, pw_w2, pw_b2, inb, dcn_wt2, h, wq, 0, 88,
                          acc0, acc1, acc2, acc3);
        store_raw(outbuf + (size_t)((b * 3 + 2) * OO) * HWP + p, acc0, acc1, acc2, acc3);
    } else {
        branch_compute<5>(dwv0, dwv1, dwv2, dwv3, pw_w2, pw_b2, inb, dcn_wt2, h, wq, 88, 175,
                          acc0, acc1, acc2, acc3);
        store_raw(part1 + (size_t)(b * OO) * HWP + p, acc0, acc1, acc2, acc3);
    }
}

// ---------------- combine: outbuf t2 = relu(partA + partB + bias) ---------
__global__ __launch_bounds__(256)
void combine_kernel(float* __restrict__ outbuf, const float* __restrict__ part1,
                    const float* __restrict__ dcn_b2) {
    int blk = blockIdx.x;
    int b = blk / PIX_BLOCKS;
    int p = (blk % PIX_BLOCKS) * 256 + threadIdx.x;
    float* op = outbuf + (size_t)((b * 3 + 2) * OO) * HWP + p;
    const float* pp = part1 + (size_t)(b * OO) * HWP + p;
#pragma unroll 8
    for (int o = 0; o < OO; ++o) {
        float v = op[(size_t)o * HWP] + pp[(size_t)o * HWP] + dcn_b2[o];
        op[(size_t)o * HWP] = v > 0.f ? v : 0.f;
    }
}

// ---------------- attention: per-block partial sums of relu(attn pw) ------
__global__ __launch_bounds__(256)
void attn_sum_kernel(const float* __restrict__ outbuf, const float* __restrict__ attn_wt,
                     const float* __restrict__ attn_b, float* __restrict__ partial) {
    int blk = blockIdx.x;
    int b = blk / PIX_BLOCKS;
    int pb = blk % PIX_BLOCKS;
    int p = pb * 256 + threadIdx.x;
    const float* ob = outbuf + (size_t)(b * 192) * HWP + p;
    f32x16 a0, a1, a2, a3;
#pragma unroll
    for (int j = 0; j < 16; ++j) {
        a0[j] = attn_b[j]; a1[j] = attn_b[16 + j]; a2[j] = attn_b[32 + j]; a3[j] = attn_b[48 + j];
    }
    for (int c = 0; c < 192; ++c) {
        float v = ob[(size_t)c * HWP];
        const float* wt = attn_wt + c * OO;
#pragma unroll
        for (int j = 0; j < 16; ++j) a0[j] += v * wt[j];
#pragma unroll
        for (int j = 0; j < 16; ++j) a1[j] += v * wt[16 + j];
#pragma unroll
        for (int j = 0; j < 16; ++j) a2[j] += v * wt[32 + j];
#pragma unroll
        for (int j = 0; j < 16; ++j) a3[j] += v * wt[48 + j];
    }
    __shared__ float red[4][OO];
    int lane = threadIdx.x & 63, wv = threadIdx.x >> 6;
#pragma unroll
    for (int o = 0; o < OO; ++o) {
        float v = (o < 16) ? a0[o & 15] : (o < 32) ? a1[o & 15] : (o < 48) ? a2[o & 15] : a3[o & 15];
        v = v > 0.f ? v : 0.f;
        v += __shfl_down(v, 32);
        v += __shfl_down(v, 16);
        v += __shfl_down(v, 8);
        v += __shfl_down(v, 4);
        v += __shfl_down(v, 2);
        v += __shfl_down(v, 1);
        if (lane == 0) red[wv][o] = v;
    }
    __syncthreads();
    if (threadIdx.x < OO) {
        int o = threadIdx.x;
        partial[(size_t)(b * PIX_BLOCKS + pb) * OO + o] =
            red[0][o] + red[1][o] + red[2][o] + red[3][o];
    }
}

// ---------------- attention finish: mean -> fc(relu) -> per-branch scales -
__global__ void attn_finish_kernel(const float* __restrict__ partial,
                                   const float* __restrict__ fc_w, const float* __restrict__ fc_b,
                                   const float* __restrict__ fcs_w0, const float* __restrict__ fcs_b0,
                                   const float* __restrict__ fcs_w1, const float* __restrict__ fcs_b1,
                                   const float* __restrict__ fcs_w2, const float* __restrict__ fcs_b2,
                                   float* __restrict__ atts) {
    int b = blockIdx.x;
    __shared__ float attm[OO];
    __shared__ float fcv[32];
    int tid = threadIdx.x;   // 64 threads
    if (tid < OO) {
        float s = 0.f;
        for (int blk = 0; blk < PIX_BLOCKS; ++blk)
            s += partial[(size_t)(b * PIX_BLOCKS + blk) * OO + tid];
        attm[tid] = s / (float)HWP;
    }
    __syncthreads();
    if (tid < 32) {
        float s = fc_b[tid];
        for (int o = 0; o < OO; ++o) s += fc_w[tid * OO + o] * attm[o];
        fcv[tid] = s > 0.f ? s : 0.f;
    }
    __syncthreads();
    if (tid < OO) {
        {
            float s = fcs_b0[tid];
            for (int j = 0; j < 32; ++j) s += fcs_w0[tid * 32 + j] * fcv[j];
            atts[b * 192 + 0 * OO + tid] = s;
        }
        {
            float s = fcs_b1[tid];
            for (int j = 0; j < 32; ++j) s += fcs_w1[tid * 32 + j] * fcv[j];
            atts[b * 192 + 1 * OO + tid] = s;
        }
        {
            float s = fcs_b2[tid];
            for (int j = 0; j < 32; ++j) s += fcs_w2[tid * 32 + j] * fcv[j];
            atts[b * 192 + 2 * OO + tid] = s;
        }
    }
}

// ---------------- final: scale + 1x1 conv + relu ----------------
__global__ __launch_bounds__(256)
void final_kernel(const float* __restrict__ outbuf, const float* __restrict__ atts,
                  const float* __restrict__ conv_wt, const float* __restrict__ conv_b,
                  float* __restrict__ out) {
    int blk = blockIdx.x;
    int b = blk / PIX_BLOCKS;
    int p = (blk % PIX_BLOCKS) * 256 + threadIdx.x;
    const float* ob = outbuf + (size_t)(b * 192) * HWP + p;
    const float* at = atts + b * 192;
    f32x16 a0, a1, a2, a3;
#pragma unroll
    for (int j = 0; j < 16; ++j) {
        a0[j] = conv_b[j]; a1[j] = conv_b[16 + j]; a2[j] = conv_b[32 + j]; a3[j] = conv_b[48 + j];
    }
    for (int c = 0; c < 192; ++c) {
        float v = ob[(size_t)c * HWP] * at[c];
        const float* wt = conv_wt + c * OO;
#pragma unroll
        for (int j = 0; j < 16; ++j) a0[j] += v * wt[j];
#pragma unroll
        for (int j = 0; j < 16; ++j) a1[j] += v * wt[16 + j];
#pragma unroll
        for (int j = 0; j < 16; ++j) a2[j] += v * wt[32 + j];
#pragma unroll
        for (int j = 0; j < 16; ++j) a3[j] += v * wt[48 + j];
    }
    float* op = out + (size_t)(b * OO) * HWP + p;
#pragma unroll
    for (int j = 0; j < 16; ++j) op[(size_t)j * HWP] = a0[j] > 0.f ? a0[j] : 0.f;
#pragma unroll
    for (int j = 0; j < 16; ++j) op[(size_t)(16 + j) * HWP] = a1[j] > 0.f ? a1[j] : 0.f;
#pragma unroll
    for (int j = 0; j < 16; ++j) op[(size_t)(32 + j) * HWP] = a2[j] > 0.f ? a2[j] : 0.f;
#pragma unroll
    for (int j = 0; j < 16; ++j) op[(size_t)(48 + j) * HWP] = a3[j] > 0.f ? a3[j] : 0.f;
}

extern "C" void kernel_launch(void* const* d_in, const int* in_sizes, int n_in,
                              void* d_out, int out_size, void* d_ws, size_t ws_size,
                              hipStream_t stream) {
    const float* fea    = (const float*)d_in[0];
    const float* inputs = (const float*)d_in[1];
    const float* dw_w[3]  = {(const float*)d_in[2],  (const float*)d_in[8],  (const float*)d_in[14]};
    const float* dw_b[3]  = {(const float*)d_in[3],  (const float*)d_in[9],  (const float*)d_in[15]};
    const float* pw_w[3]  = {(const float*)d_in[4],  (const float*)d_in[10], (const float*)d_in[16]};
    const float* pw_b[3]  = {(const float*)d_in[5],  (const float*)d_in[11], (const float*)d_in[17]};
    const float* dcn_w[3] = {(const float*)d_in[6],  (const float*)d_in[12], (const float*)d_in[18]};
    const float* dcn_b[3] = {(const float*)d_in[7],  (const float*)d_in[13], (const float*)d_in[19]};
    const float* attn_w = (const float*)d_in[20];
    const float* attn_b = (const float*)d_in[21];
    const float* fc_w   = (const float*)d_in[22];
    const float* fc_b   = (const float*)d_in[23];
    const float* fcs_w[3] = {(const float*)d_in[24], (const float*)d_in[26], (const float*)d_in[28]};
    const float* fcs_b[3] = {(const float*)d_in[25], (const float*)d_in[27], (const float*)d_in[29]};
    const float* conv_w = (const float*)d_in[30];
    const float* conv_b = (const float*)d_in[31];
    float* out = (float*)d_out;

    // big path needs: outbuf + 2 dw planes + small = ~189 MB
    const size_t F_OUTBUF = 28311552, F_DW = 9437184;
    const size_t F_SMALL = 36864 + 768 + 512 + 4096 + 11264 + 12288 + 12288;
    size_t need_big = (F_OUTBUF + 2 * F_DW + F_SMALL) * 4;
    bool big = ws_size >= need_big;

    float* W = (float*)d_ws;
    float* outbuf = W;            W += F_OUTBUF;
    float* dw3out, * dw5out;
    if (big) { dw3out = W; W += F_DW; dw5out = W; W += F_DW; }
    else     { dw3out = W; dw5out = W; W += F_DW; }
    float* partial = W;           W += 36864;
    float* atts = W;              W += 768;
    float* dcn_wt0 = W;           W += 512;
    float* dcn_wt1 = W;           W += 4096;
    float* dcn_wt2 = W;           W += 11264;
    float* attn_wt = W;           W += 12288;
    float* conv_wt = W;           W += 12288;
    float* part1 = out;           // d_out doubles as k5-partial scratch; final_kernel
                                  // fully rewrites d_out afterwards (deterministic)

    // weight transposes
    transpose_kernel<<<(192 * 64 + 255) / 256, 256, 0, stream>>>(attn_w, attn_wt, 64, 192);
    transpose_kernel<<<(192 * 64 + 255) / 256, 256, 0, stream>>>(conv_w, conv_wt, 64, 192);
    transpose_kernel<<<(7 * 64 + 255) / 256, 256, 0, stream>>>(dcn_w[0], dcn_wt0, 64, 7);
    transpose_kernel<<<(63 * 64 + 255) / 256, 256, 0, stream>>>(dcn_w[1], dcn_wt1, 64, 63);
    transpose_kernel<<<(175 * 64 + 255) / 256, 256, 0, stream>>>(dcn_w[2], dcn_wt2, 64, 175);

    const int dw_grid = (BB * CF * HWP) / 256;   // 36864
    const int pix_grid = BB * PIX_BLOCKS;        // 576

    if (big) {
        dw35_kernel<<<dw_grid, 256, 0, stream>>>(fea, dw_w[1], dw_b[1], dw_w[2], dw_b[2],
                                                 dw3out, dw5out);
        mega_branch_kernel<<<4 * pix_grid, 256, 0, stream>>>(
            fea, dw_w[0], dw_b[0], dw3out, dw5out,
            pw_w[0], pw_b[0], pw_w[1], pw_b[1], pw_w[2], pw_b[2],
            inputs, dcn_wt0, dcn_b[0], dcn_wt1, dcn_b[1], dcn_wt2,
            outbuf, part1, -1);
    } else {
        // sequential fallback: shared dw buffer, one kind at a time
        mega_branch_kernel<<<pix_grid, 256, 0, stream>>>(
            fea, dw_w[0], dw_b[0], dw3out, dw5out,
            pw_w[0], pw_b[0], pw_w[1], pw_b[1], pw_w[2], pw_b[2],
            inputs, dcn_wt0, dcn_b[0], dcn_wt1, dcn_b[1], dcn_wt2,
            outbuf, part1, 3);
        dw_kernel<3><<<dw_grid, 256, 0, stream>>>(fea, dw_w[1], dw_b[1], dw3out);
        mega_branch_kernel<<<pix_grid, 256, 0, stream>>>(
            fea, dw_w[0], dw_b[0], dw3out, dw5out,
            pw_w[0], pw_b[0], pw_w[1], pw_b[1], pw_w[2], pw_b[2],
            inputs, dcn_wt0, dcn_b[0], dcn_wt1, dcn_b[1], dcn_wt2,
            outbuf, part1, 2);
        dw_kernel<5><<<dw_grid, 256, 0, stream>>>(fea, dw_w[2], dw_b[2], dw5out);
        mega_branch_kernel<<<pix_grid, 256, 0, stream>>>(
            fea, dw_w[0], dw_b[0], dw3out, dw5out,
            pw_w[0], pw_b[0], pw_w[1], pw_b[1], pw_w[2], pw_b[2],
            inputs, dcn_wt0, dcn_b[0], dcn_wt1, dcn_b[1], dcn_wt2,
            outbuf, part1, 0);
        mega_branch_kernel<<<pix_grid, 256, 0, stream>>>(
            fea, dw_w[0], dw_b[0], dw3out, dw5out,
            pw_w[0], pw_b[0], pw_w[1], pw_b[1], pw_w[2], pw_b[2],
            inputs, dcn_wt0, dcn_b[0], dcn_wt1, dcn_b[1], dcn_wt2,
            outbuf, part1, 1);
    }
    combine_kernel<<<pix_grid, 256, 0, stream>>>(outbuf, part1, dcn_b[2]);

    // attention + final
    attn_sum_kernel<<<pix_grid, 256, 0, stream>>>(outbuf, attn_wt, attn_b, partial);
    attn_finish_kernel<<<BB, 64, 0, stream>>>(partial, fc_w, fc_b,
                                              fcs_w[0], fcs_b[0], fcs_w[1], fcs_b[1],
                                              fcs_w[2], fcs_b[2], atts);
    final_kernel<<<pix_grid, 256, 0, stream>>>(outbuf, atts, conv_wt, conv_b, out);
}